// Round 5
// baseline (424.388 us; speedup 1.0000x reference)
//
#include <hip/hip_runtime.h>

#define TSEQ 512
#define BSZN 4
#define NH 16
#define NBN 32
#define EMB 1024
#define HD 64
#define TGT 1536
#define MROWS 6144

typedef unsigned short ushort_t;
typedef __bf16 bf8 __attribute__((ext_vector_type(8)));
typedef unsigned short u16x4 __attribute__((ext_vector_type(4)));
typedef float f32x4 __attribute__((ext_vector_type(4)));

__device__ __forceinline__ unsigned short f2bf(float f) {
  unsigned int u = __builtin_bit_cast(unsigned int, f);
  u += 0x7fffu + ((u >> 16) & 1u);
  return (unsigned short)(u >> 16);
}

__device__ __forceinline__ float bf2f(unsigned short u) {
  return __builtin_bit_cast(float, (unsigned int)u << 16);
}

__device__ __forceinline__ void gload16(const void* g, void* l) {
  __builtin_amdgcn_global_load_lds(
      (const __attribute__((address_space(1))) void*)g,
      (__attribute__((address_space(3))) void*)l, 16, 0, 0);
}

__device__ __forceinline__ f32x4 mfma_bf16(bf8 a, bf8 b, f32x4 c) {
  return __builtin_amdgcn_mfma_f32_16x16x32_bf16(a, b, c, 0, 0, 0);
}

__device__ __forceinline__ float lanebcast(float v, int srclane) {
  return __builtin_bit_cast(float,
      __builtin_amdgcn_ds_bpermute(srclane * 4, __builtin_bit_cast(int, v)));
}

// ---------------- fp32 -> bf16 convert (6 segments incl. masks) ----------------
__global__ void cvt6_kernel(const float* __restrict__ q, const float* __restrict__ win,
                            const float* __restrict__ wout, const float* __restrict__ wrel,
                            const float* __restrict__ mm, const float* __restrict__ mng,
                            ushort_t* __restrict__ qo, ushort_t* __restrict__ wino,
                            ushort_t* __restrict__ wouto, ushort_t* __restrict__ wrelo,
                            ushort_t* __restrict__ mmo, ushort_t* __restrict__ mngo) {
  const int i = blockIdx.x * blockDim.x + threadIdx.x;
  const int n0 = 1572864, n1 = 786432, n2 = 262144, n3 = 131072, n4 = 65536, n5 = 262144;
  const float* src;
  ushort_t* dst;
  int off;
  if (i < n0) { src = q; dst = qo; off = i; }
  else if (i < n0 + n1) { src = win; dst = wino; off = i - n0; }
  else if (i < n0 + n1 + n2) { src = wout; dst = wouto; off = i - n0 - n1; }
  else if (i < n0 + n1 + n2 + n3) { src = wrel; dst = wrelo; off = i - n0 - n1 - n2; }
  else if (i < n0 + n1 + n2 + n3 + n4) { src = mm; dst = mmo; off = i - n0 - n1 - n2 - n3; }
  else if (i < n0 + n1 + n2 + n3 + n4 + n5) { src = mng; dst = mngo; off = i - n0 - n1 - n2 - n3 - n4; }
  else return;
  const float4 v = reinterpret_cast<const float4*>(src)[off];
  ushort4 o;
  o.x = f2bf(v.x); o.y = f2bf(v.y); o.z = f2bf(v.z); o.w = f2bf(v.w);
  reinterpret_cast<ushort4*>(dst)[off] = o;
}

// ---------------- bucket indices int32 -> u8 (values < 32) ----------------
__global__ void prep_ib_kernel(const int* __restrict__ ibm, const int* __restrict__ ibr,
                               unsigned char* __restrict__ obm, unsigned char* __restrict__ obr) {
  const int i = blockIdx.x * blockDim.x + threadIdx.x;
  const int nm4 = 262144, nr4 = 524288;
  if (i < nm4) {
    const int4 v = reinterpret_cast<const int4*>(ibm)[i];
    uchar4 o;
    o.x = (unsigned char)v.x; o.y = (unsigned char)v.y;
    o.z = (unsigned char)v.z; o.w = (unsigned char)v.w;
    reinterpret_cast<uchar4*>(obm)[i] = o;
  } else if (i < nm4 + nr4) {
    const int j = i - nm4;
    const int4 v = reinterpret_cast<const int4*>(ibr)[j];
    uchar4 o;
    o.x = (unsigned char)v.x; o.y = (unsigned char)v.y;
    o.z = (unsigned char)v.z; o.w = (unsigned char)v.w;
    reinterpret_cast<uchar4*>(obr)[j] = o;
  }
}

// ---------------- GEMM: C[M,N] = A[M,K] * B[N,K]^T + bias ----------------
template <int MODE>
__global__ __launch_bounds__(256) void gemm_bt(
    const ushort_t* __restrict__ A, const ushort_t* __restrict__ B,
    const float* __restrict__ bias, float* __restrict__ Cf,
    ushort_t* __restrict__ Qo, ushort_t* __restrict__ Ko, ushort_t* __restrict__ Vto,
    int M, int N, int K) {
  __shared__ ushort_t lA[128 * 32];
  __shared__ ushort_t lB[128 * 32];
  const int tid = threadIdx.x;
  const int lane = tid & 63;
  const int wid = tid >> 6;
  const int l15 = lane & 15, l4 = lane >> 4;
  const int bm = blockIdx.y, bn = blockIdx.x;
  const int wm = (wid >> 1) * 64, wn = (wid & 1) * 64;

  f32x4 acc[4][4] = {};

  const int srow = tid >> 2;
  const int scol = (tid & 3) * 8;
  const ushort_t* Ag = A + (size_t)(bm * 128 + srow) * K + scol;
  const ushort_t* Bg = B + (size_t)(bn * 128 + srow) * K + scol;
  ushort_t* lAp = &lA[srow * 32 + scol];
  ushort_t* lBp = &lB[srow * 32 + scol];

  for (int kt = 0; kt < K; kt += 32) {
    __syncthreads();
    gload16(Ag + kt, lAp);
    gload16(Ag + kt + (size_t)64 * K, lAp + 64 * 32);
    gload16(Bg + kt, lBp);
    gload16(Bg + kt + (size_t)64 * K, lBp + 64 * 32);
    __syncthreads();
    bf8 af[4], bv[4];
#pragma unroll
    for (int mi = 0; mi < 4; ++mi)
      af[mi] = *reinterpret_cast<const bf8*>(&lA[(wm + mi * 16 + l15) * 32 + l4 * 8]);
#pragma unroll
    for (int ni = 0; ni < 4; ++ni)
      bv[ni] = *reinterpret_cast<const bf8*>(&lB[(wn + ni * 16 + l15) * 32 + l4 * 8]);
#pragma unroll
    for (int mi = 0; mi < 4; ++mi)
#pragma unroll
      for (int ni = 0; ni < 4; ++ni)
        acc[mi][ni] = mfma_bf16(af[mi], bv[ni], acc[mi][ni]);
  }

#pragma unroll
  for (int ni = 0; ni < 4; ++ni) {
    const int col = bn * 128 + wn + ni * 16 + l15;
    const float bc = bias[col];
#pragma unroll
    for (int mi = 0; mi < 4; ++mi) {
      const int row0 = bm * 128 + wm + mi * 16 + l4 * 4;
      f32x4 v = acc[mi][ni];
#pragma unroll
      for (int r = 0; r < 4; ++r) {
        const int row = row0 + r;
        float val = v[r] + bc;
        if (MODE == 0) {
          const int part = col >> 10;
          const int cc = col & 1023;
          const int h = cc >> 6, d = cc & 63;
          const int t = row >> 2, bb = row & 3;
          const int bh = bb * NH + h;
          if (part == 0) {
            Qo[((size_t)bh * TGT + t) * HD + d] = f2bf(val * 0.125f);
          } else if (part == 1) {
            Ko[((size_t)bh * TGT + t) * HD + d] = f2bf(val);
          } else {
            Vto[((size_t)bh * HD + d) * TGT + t] = f2bf(val);
          }
        } else if (MODE == 3) {
          Qo[(size_t)row * N + col] = f2bf(val);
        } else {
          Cf[(size_t)row * N + col] = val;
        }
      }
    }
  }
}

// ---------------- fused attention: one wave per (b,h,tile,z), no barriers ----------------
// grid 1536 blocks x 256. XCD-pair 2b,2b+1 owns batch b. Waves in a block =
// 4 adjacent tiles of the same (b,h,z) -> K/V panel L1/L2 reuse.
__global__ __launch_bounds__(256) void attn_kernel(
    const ushort_t* __restrict__ Q, const ushort_t* __restrict__ Kb,
    const ushort_t* __restrict__ Vt, const ushort_t* __restrict__ VMb,
    const unsigned char* __restrict__ ib8_main, const unsigned char* __restrict__ ib8_rel,
    const ushort_t* __restrict__ mmb, const ushort_t* __restrict__ mngb,
    ushort_t* __restrict__ AT) {
  // per-wave LDS: VM table f32[16][33] (528 dw) + P bf16[16][66] (528 dw)
  __shared__ unsigned int ldsbuf[4224];

  const int tid = threadIdx.x;
  const int lane = tid & 63, wid = tid >> 6;
  const int l15 = lane & 15, l4 = lane >> 4;

  const int n = blockIdx.x;
  const int xcd = n & 7;
  const int b = xcd >> 1;
  const int idx = ((xcd & 1) * 192) + (n >> 3);  // [0,384)
  const int task = idx * 4 + wid;                // [0,1536)
  const int tile = task & 31;
  const int rest = task >> 5;                    // [0,48)
  const int z = rest % 3;
  const int h = rest / 3;
  const int g = (z == 0) ? 0 : z - 1;
  const int bh = b * NH + h;
  const int t0 = tile * 16;
  const int qrow0 = (z == 0) ? t0 : TSEQ + g * TSEQ + t0;
  const int nsb = (z == 0) ? 8 : 16;

  unsigned int* wbase = ldsbuf + wid * 1056;
  float* vmt = reinterpret_cast<float*>(wbase);          // [16][33] f32
  unsigned int* pb = wbase + 528;                        // [16][33] dwords
  ushort_t* pbu = reinterpret_cast<ushort_t*>(pb);       // [16][66] u16

  // ---- stage this wave's VM table: vmt[t][ib] = VM[qrow0+t][b][ib][h]
#pragma unroll
  for (int p = 0; p < 8; ++p) {
    const int ib = l4 * 8 + p;
    const float v = bf2f(VMb[((size_t)(qrow0 + l15) * BSZN + b) * (NBN * NH) + ib * NH + h]);
    vmt[l15 * 33 + ib] = v;
  }

  // ---- Q fragments (B-operand): lane t = l15, k = d
  const ushort_t* qp = &Q[((size_t)bh * TGT + qrow0 + l15) * HD + l4 * 8];
  const bf8 qf0 = *reinterpret_cast<const bf8*>(qp);
  const bf8 qf1 = *reinterpret_cast<const bf8*>(qp + 32);

  // per-lane row pointers for ib/mask (row = this lane's t = l15)
  const unsigned char* ibrow = (z == 0)
      ? ib8_main + (size_t)b * TSEQ * TSEQ + (size_t)(t0 + l15) * TSEQ
      : ib8_rel + (size_t)b * TSEQ * (2 * TSEQ) + (size_t)(t0 + l15) * (2 * TSEQ);
  const ushort_t* mrow = (z == 0)
      ? mmb + (size_t)(t0 + l15) * TSEQ
      : mngb + ((size_t)g * TSEQ + t0 + l15) * (2 * TSEQ);

  float m_run = -1e30f, l_run = 0.f;
  f32x4 oacc[4] = {};

  for (int sb = 0; sb < nsb; ++sb) {
    const int srow0 = (sb < 8) ? sb * 64 : TSEQ + g * TSEQ + (sb - 8) * 64;
    const int scol = sb * 64;

    // ---- K^T Q MFMA: st[j] = S^T tile, lane holds col t=l15, rows s over regs
    f32x4 st[4];
#pragma unroll
    for (int j = 0; j < 4; ++j) {
      const ushort_t* kp = &Kb[((size_t)bh * TGT + srow0 + j * 16 + l15) * HD + l4 * 8];
      const bf8 kf0 = *reinterpret_cast<const bf8*>(kp);
      const bf8 kf1 = *reinterpret_cast<const bf8*>(kp + 32);
      f32x4 s4 = {};
      s4 = mfma_bf16(kf0, qf0, s4);
      s4 = mfma_bf16(kf1, qf1, s4);
      st[j] = s4;
    }

    // ---- bucket + mask loads for this lane's 16 s-values (s = scol+j*16+l4*4+r)
    unsigned int ibw[4];
    u16x4 mkv[4];
#pragma unroll
    for (int j = 0; j < 4; ++j) {
      ibw[j] = *reinterpret_cast<const unsigned int*>(ibrow + scol + j * 16 + l4 * 4);
      mkv[j] = *reinterpret_cast<const u16x4*>(mrow + scol + j * 16 + l4 * 4);
    }

    // ---- vals + max
    float vals[4][4];
    float mx = -1e30f;
#pragma unroll
    for (int j = 0; j < 4; ++j) {
#pragma unroll
      for (int r = 0; r < 4; ++r) {
        const int ib = (int)((ibw[j] >> (8 * r)) & 31u);
        const float v = st[j][r] + bf2f(mkv[j][r]) + vmt[l15 * 33 + ib];
        vals[j][r] = v;
        mx = fmaxf(mx, v);
      }
    }
    mx = fmaxf(mx, __shfl_xor(mx, 16));
    mx = fmaxf(mx, __shfl_xor(mx, 32));

    const float newm = fmaxf(m_run, mx);
    const float fct = (m_run <= -1e30f) ? 0.f : __expf(m_run - newm);

    // ---- exp + sum + pack P^T -> per-wave LDS as P[t][s]
    float lsum = 0.f;
#pragma unroll
    for (int j = 0; j < 4; ++j) {
#pragma unroll
      for (int r = 0; r < 4; ++r) {
        const float p = __expf(vals[j][r] - newm);
        vals[j][r] = p;
        lsum += p;
      }
    }
    lsum += __shfl_xor(lsum, 16);
    lsum += __shfl_xor(lsum, 32);
    l_run = l_run * fct + lsum;
    m_run = newm;

#pragma unroll
    for (int j = 0; j < 4; ++j) {
#pragma unroll
      for (int pr = 0; pr < 2; ++pr) {
        const unsigned int lo = f2bf(vals[j][2 * pr]);
        const unsigned int hi = f2bf(vals[j][2 * pr + 1]);
        pb[l15 * 33 + j * 8 + l4 * 2 + pr] = lo | (hi << 16);
      }
    }

    // ---- rescale oacc (factor per output row t = l4*4+r, pulled from lane t)
    float frr[4];
#pragma unroll
    for (int r = 0; r < 4; ++r) frr[r] = lanebcast(fct, l4 * 4 + r);
#pragma unroll
    for (int dt = 0; dt < 4; ++dt)
#pragma unroll
      for (int r = 0; r < 4; ++r) oacc[dt][r] *= frr[r];

    // ---- PV: A = P[t][s] (from LDS), B = Vt[d][s] (global), C[t][d]
#pragma unroll
    for (int k32 = 0; k32 < 2; ++k32) {
      const bf8 pa = *reinterpret_cast<const bf8*>(pbu + l15 * 66 + k32 * 32 + l4 * 8);
#pragma unroll
      for (int dt = 0; dt < 4; ++dt) {
        const bf8 vb = *reinterpret_cast<const bf8*>(
            &Vt[((size_t)bh * HD + dt * 16 + l15) * TGT + srow0 + k32 * 32 + l4 * 8]);
        oacc[dt] = mfma_bf16(pa, vb, oacc[dt]);
      }
    }
  }

  // ---- epilogue: divide by l (per row t = l4*4+r) and store
  const float linv = 1.f / l_run;
  float brr[4];
#pragma unroll
  for (int r = 0; r < 4; ++r) brr[r] = lanebcast(linv, l4 * 4 + r);
#pragma unroll
  for (int dt = 0; dt < 4; ++dt) {
#pragma unroll
    for (int r = 0; r < 4; ++r) {
      const int tout = qrow0 + l4 * 4 + r;
      AT[((size_t)tout * BSZN + b) * EMB + h * HD + dt * 16 + l15] =
          f2bf(oacc[dt][r] * brr[r]);
    }
  }
}

extern "C" void kernel_launch(void* const* d_in, const int* in_sizes, int n_in,
                              void* d_out, int out_size, void* d_ws, size_t ws_size,
                              hipStream_t stream) {
  const float* query     = (const float*)d_in[0];
  const float* mask_main = (const float*)d_in[1];
  const float* mask_ng   = (const float*)d_in[2];
  const int*   ib_main   = (const int*)d_in[3];
  const int*   ib_rel    = (const int*)d_in[4];
  const float* w_in      = (const float*)d_in[5];
  const float* b_in      = (const float*)d_in[6];
  const float* w_out     = (const float*)d_in[7];
  const float* b_out     = (const float*)d_in[8];
  const float* w_rel     = (const float*)d_in[9];
  const float* b_rel     = (const float*)d_in[10];
  float* out = (float*)d_out;

  // workspace layout (u16 units); AT aliases qbf (dead after the VM gemm)
  ushort_t* qbf    = (ushort_t*)d_ws;           // 6291456
  ushort_t* winbf  = qbf + 6291456;             // 3145728
  ushort_t* woutbf = winbf + 3145728;           // 1048576
  ushort_t* relwbf = woutbf + 1048576;          // 524288
  ushort_t* Qb     = relwbf + 524288;           // 6291456
  ushort_t* Kbuf   = Qb + 6291456;              // 6291456
  ushort_t* Vtb    = Kbuf + 6291456;            // 6291456
  ushort_t* VMb    = Vtb + 6291456;             // 3145728
  ushort_t* mmb    = VMb + 3145728;             // 262144
  ushort_t* mngb   = mmb + 262144;              // 1048576
  unsigned char* ib8_main = (unsigned char*)(mngb + 1048576);   // 1048576 B
  unsigned char* ib8_rel  = ib8_main + 1048576;                 // 2097152 B
  ushort_t* AT     = qbf;                       // alias

  // fp32 -> bf16 (query, weights, masks)
  {
    const int total4 = 1572864 + 786432 + 262144 + 131072 + 65536 + 262144;
    cvt6_kernel<<<total4 / 256, 256, 0, stream>>>(query, w_in, w_out, w_rel,
                                                  mask_main, mask_ng,
                                                  qbf, winbf, woutbf, relwbf, mmb, mngb);
  }
  // bucket indices -> u8
  prep_ib_kernel<<<(262144 + 524288) / 256, 256, 0, stream>>>(ib_main, ib_rel,
                                                              ib8_main, ib8_rel);

  // in-projection -> Q/K/Vt
  gemm_bt<0><<<dim3(24, 48), 256, 0, stream>>>(qbf, winbf, b_in, nullptr,
                                               Qb, Kbuf, Vtb, MROWS, 3072, 1024);
  // relative-value table VM (bf16)
  gemm_bt<3><<<dim3(4, 48), 256, 0, stream>>>(qbf, relwbf, b_rel, nullptr,
                                              VMb, nullptr, nullptr, MROWS, 512, 1024);
  // fused attention: one wave per (b,h,tile,z), no barriers
  attn_kernel<<<1536, 256, 0, stream>>>(Qb, Kbuf, Vtb, VMb, ib8_main, ib8_rel,
                                        mmb, mngb, AT);
  // out-projection
  gemm_bt<2><<<dim3(8, 48), 256, 0, stream>>>(AT, woutbf, b_out, out,
                                              nullptr, nullptr, nullptr, MROWS, 1024, 1024);
}

// Round 6
// 244.246 us; speedup vs baseline: 1.7375x; 1.7375x over previous
//
#include <hip/hip_runtime.h>

#define TSEQ 512
#define BSZN 4
#define NH 16
#define NBN 32
#define EMB 1024
#define HD 64
#define TGT 1536
#define MROWS 6144

typedef unsigned short ushort_t;
typedef __bf16 bf8 __attribute__((ext_vector_type(8)));
typedef float f32x4 __attribute__((ext_vector_type(4)));

__device__ __forceinline__ unsigned short f2bf(float f) {
  unsigned int u = __builtin_bit_cast(unsigned int, f);
  u += 0x7fffu + ((u >> 16) & 1u);
  return (unsigned short)(u >> 16);
}

__device__ __forceinline__ float bf2f(unsigned short u) {
  return __builtin_bit_cast(float, (unsigned int)u << 16);
}

__device__ __forceinline__ unsigned int packbf(float a, float b) {
  return (unsigned int)f2bf(a) | ((unsigned int)f2bf(b) << 16);
}

__device__ __forceinline__ void gload16(const void* g, void* l) {
  __builtin_amdgcn_global_load_lds(
      (const __attribute__((address_space(1))) void*)g,
      (__attribute__((address_space(3))) void*)l, 16, 0, 0);
}

__device__ __forceinline__ f32x4 mfma_bf16(bf8 a, bf8 b, f32x4 c) {
  return __builtin_amdgcn_mfma_f32_16x16x32_bf16(a, b, c, 0, 0, 0);
}

__device__ __forceinline__ float lanebcast(float v, int srclane) {
  return __builtin_bit_cast(float,
      __builtin_amdgcn_ds_bpermute(srclane * 4, __builtin_bit_cast(int, v)));
}

// ---------------- fp32 -> bf16 convert (4 segments) ----------------
__global__ void cvt4_kernel(const float* __restrict__ q, const float* __restrict__ win,
                            const float* __restrict__ wout, const float* __restrict__ wrel,
                            ushort_t* __restrict__ qo, ushort_t* __restrict__ wino,
                            ushort_t* __restrict__ wouto, ushort_t* __restrict__ wrelo) {
  const int i = blockIdx.x * blockDim.x + threadIdx.x;
  const int n0 = 1572864, n1 = 786432, n2 = 262144, n3 = 131072;
  const float* src;
  ushort_t* dst;
  int off;
  if (i < n0) { src = q; dst = qo; off = i; }
  else if (i < n0 + n1) { src = win; dst = wino; off = i - n0; }
  else if (i < n0 + n1 + n2) { src = wout; dst = wouto; off = i - n0 - n1; }
  else if (i < n0 + n1 + n2 + n3) { src = wrel; dst = wrelo; off = i - n0 - n1 - n2; }
  else return;
  const float4 v = reinterpret_cast<const float4*>(src)[off];
  ushort4 o;
  o.x = f2bf(v.x); o.y = f2bf(v.y); o.z = f2bf(v.z); o.w = f2bf(v.w);
  reinterpret_cast<ushort4*>(dst)[off] = o;
}

// ---------------- combined (bf16 mask << 16) | bucket  ----------------
// comb_main[b][t][s] (u32, 4*512*512); comb_ng[b*2+g][t][s2] (u32, 8*512*1024)
__global__ void prep_comb_kernel(const int* __restrict__ ibm, const int* __restrict__ ibr,
                                 const float* __restrict__ mm, const float* __restrict__ mng,
                                 unsigned int* __restrict__ cm, unsigned int* __restrict__ cng) {
  const int i = blockIdx.x * blockDim.x + threadIdx.x;
  const int nm = 262144;   // main u32x4 groups
  const int nr = 1048576;  // ng u32x4 groups
  if (i < nm) {
    const int f = i * 4;
    const int4 ib = *reinterpret_cast<const int4*>(ibm + f);
    const float4 mk = *reinterpret_cast<const float4*>(mm + (f & 262143));
    uint4 o;
    o.x = ((unsigned int)f2bf(mk.x) << 16) | ((unsigned int)ib.x & 31u);
    o.y = ((unsigned int)f2bf(mk.y) << 16) | ((unsigned int)ib.y & 31u);
    o.z = ((unsigned int)f2bf(mk.z) << 16) | ((unsigned int)ib.z & 31u);
    o.w = ((unsigned int)f2bf(mk.w) << 16) | ((unsigned int)ib.w & 31u);
    *reinterpret_cast<uint4*>(cm + f) = o;
  } else if (i < nm + nr) {
    const int f = (i - nm) * 4;
    // f = (b*2+g)*2^19 + t*1024 + s2
    const int ib_off = ((f >> 20) << 19) + (f & 524287);   // b*2^19 + in-slab
    const int mk_off = f & 1048575;                        // g*2^19 + in-slab
    const int4 ib = *reinterpret_cast<const int4*>(ibr + ib_off);
    const float4 mk = *reinterpret_cast<const float4*>(mng + mk_off);
    uint4 o;
    o.x = ((unsigned int)f2bf(mk.x) << 16) | ((unsigned int)ib.x & 31u);
    o.y = ((unsigned int)f2bf(mk.y) << 16) | ((unsigned int)ib.y & 31u);
    o.z = ((unsigned int)f2bf(mk.z) << 16) | ((unsigned int)ib.z & 31u);
    o.w = ((unsigned int)f2bf(mk.w) << 16) | ((unsigned int)ib.w & 31u);
    *reinterpret_cast<uint4*>(cng + f) = o;
  }
}

// ---------------- GEMM: C[M,N] = A[M,K] * B[N,K]^T + bias ----------------
// MODE 0: qkv proj -> Q(scaled)/K [bh][t][hd], Vt [bh][hd][t] (bf16)
// MODE 2: fp32 C
// MODE 3: bf16 VMh layout [b*16+h][qglob][nb]
template <int MODE>
__global__ __launch_bounds__(256) void gemm_bt(
    const ushort_t* __restrict__ A, const ushort_t* __restrict__ B,
    const float* __restrict__ bias, float* __restrict__ Cf,
    ushort_t* __restrict__ Qo, ushort_t* __restrict__ Ko, ushort_t* __restrict__ Vto,
    int M, int N, int K) {
  __shared__ ushort_t lA[128 * 32];
  __shared__ ushort_t lB[128 * 32];
  const int tid = threadIdx.x;
  const int lane = tid & 63;
  const int wid = tid >> 6;
  const int l15 = lane & 15, l4 = lane >> 4;
  const int bm = blockIdx.y, bn = blockIdx.x;
  const int wm = (wid >> 1) * 64, wn = (wid & 1) * 64;

  f32x4 acc[4][4] = {};

  const int srow = tid >> 2;
  const int scol = (tid & 3) * 8;
  const ushort_t* Ag = A + (size_t)(bm * 128 + srow) * K + scol;
  const ushort_t* Bg = B + (size_t)(bn * 128 + srow) * K + scol;
  ushort_t* lAp = &lA[srow * 32 + scol];
  ushort_t* lBp = &lB[srow * 32 + scol];

  for (int kt = 0; kt < K; kt += 32) {
    __syncthreads();
    gload16(Ag + kt, lAp);
    gload16(Ag + kt + (size_t)64 * K, lAp + 64 * 32);
    gload16(Bg + kt, lBp);
    gload16(Bg + kt + (size_t)64 * K, lBp + 64 * 32);
    __syncthreads();
    bf8 af[4], bv[4];
#pragma unroll
    for (int mi = 0; mi < 4; ++mi)
      af[mi] = *reinterpret_cast<const bf8*>(&lA[(wm + mi * 16 + l15) * 32 + l4 * 8]);
#pragma unroll
    for (int ni = 0; ni < 4; ++ni)
      bv[ni] = *reinterpret_cast<const bf8*>(&lB[(wn + ni * 16 + l15) * 32 + l4 * 8]);
#pragma unroll
    for (int mi = 0; mi < 4; ++mi)
#pragma unroll
      for (int ni = 0; ni < 4; ++ni)
        acc[mi][ni] = mfma_bf16(af[mi], bv[ni], acc[mi][ni]);
  }

#pragma unroll
  for (int ni = 0; ni < 4; ++ni) {
    const int col = bn * 128 + wn + ni * 16 + l15;
    const float bc = bias[col];
#pragma unroll
    for (int mi = 0; mi < 4; ++mi) {
      const int row0 = bm * 128 + wm + mi * 16 + l4 * 4;
      f32x4 v = acc[mi][ni];
#pragma unroll
      for (int r = 0; r < 4; ++r) {
        const int row = row0 + r;
        float val = v[r] + bc;
        if (MODE == 0) {
          const int part = col >> 10;
          const int cc = col & 1023;
          const int h = cc >> 6, d = cc & 63;
          const int t = row >> 2, bb = row & 3;
          const int bh = bb * NH + h;
          if (part == 0) {
            Qo[((size_t)bh * TGT + t) * HD + d] = f2bf(val * 0.125f);
          } else if (part == 1) {
            Ko[((size_t)bh * TGT + t) * HD + d] = f2bf(val);
          } else {
            Vto[((size_t)bh * HD + d) * TGT + t] = f2bf(val);
          }
        } else if (MODE == 3) {
          const int hh = col & 15, nb = col >> 4;
          const int qg = row >> 2, bb2 = row & 3;
          Qo[(((size_t)(bb2 * NH + hh)) * TGT + qg) * NBN + nb] = f2bf(val);
        } else {
          Cf[(size_t)row * N + col] = val;
        }
      }
    }
  }
}

// ---------------- fused attention: block = (b,h,z,128 q-rows), 4 waves x 32 rows ----------
// K/V subblocks LDS-staged once per block, shared by all 4 waves. XOR-swizzled.
__global__ __launch_bounds__(256, 3) void attn_kernel(
    const ushort_t* __restrict__ Q, const ushort_t* __restrict__ Kb,
    const ushort_t* __restrict__ Vt, const ushort_t* __restrict__ VMh,
    const unsigned int* __restrict__ comb_main, const unsigned int* __restrict__ comb_ng,
    ushort_t* __restrict__ AT) {
  __shared__ unsigned char kbuf[8192];   // K subblock [64 s][64 d] bf16, swizzled
  __shared__ unsigned char vbuf[8192];   // V subblock [64 d][64 s] bf16, swizzled
  __shared__ ushort_t vmt[4][1024];      // per wave [32 t][32 nb] bf16, linear
  __shared__ unsigned int pbl[4][1152];  // per wave, 2 th x [16 t][36 dw]

  const int tid = threadIdx.x;
  const int lane = tid & 63, wid = tid >> 6;
  const int l15 = lane & 15, l4 = lane >> 4;

  const int n = blockIdx.x;
  const int xcd = n & 7;
  const int b = xcd >> 1;
  const int idx = (xcd & 1) * 96 + (n >> 3);   // [0,192)
  const int h = idx / 12;
  const int rem = idx - h * 12;
  const int z = rem >> 2;
  const int blk = rem & 3;
  const int g = (z == 0) ? 0 : z - 1;
  const int bh = b * NH + h;
  const int t0 = blk * 128 + wid * 32;                     // stream-local q start
  const int qrow0 = (z == 0) ? t0 : TSEQ + g * TSEQ + t0;  // global q row
  const int nsb = (z == 0) ? 8 : 16;

  // ---- stage this wave's VM slab: vmt[wid][t][nb] (coalesced, linear dest)
  gload16(VMh + ((size_t)bh * TGT + qrow0 + (lane >> 2)) * NBN + (lane & 3) * 8,
          (ushort_t*)vmt[wid] + lane * 8);
  gload16(VMh + ((size_t)bh * TGT + qrow0 + 16 + (lane >> 2)) * NBN + (lane & 3) * 8,
          (ushort_t*)vmt[wid] + 512 + lane * 8);

  // ---- Q fragments (B-operand): lane t-col = l15, per half-tile th
  bf8 qf[2][2];
#pragma unroll
  for (int th = 0; th < 2; ++th)
#pragma unroll
    for (int hf = 0; hf < 2; ++hf)
      qf[th][hf] = *reinterpret_cast<const bf8*>(
          &Q[((size_t)bh * TGT + qrow0 + th * 16 + l15) * HD + hf * 32 + l4 * 8]);

  // ---- combined ib+mask row pointers (lane's t rows)
  const unsigned int* cb[2];
  {
    const unsigned int* cbase = (z == 0)
        ? comb_main + (size_t)b * TSEQ * TSEQ
        : comb_ng + (size_t)(b * 2 + g) * TSEQ * (2 * TSEQ);
    const int sstr = (z == 0) ? TSEQ : 2 * TSEQ;
    cb[0] = cbase + (size_t)(t0 + l15) * sstr;
    cb[1] = cbase + (size_t)(t0 + 16 + l15) * sstr;
  }

  float m_run[2] = {-1e30f, -1e30f};
  float l_run[2] = {0.f, 0.f};
  f32x4 oacc[2][4] = {};

  const int r8 = lane >> 3;                        // staging row-in-8
  const int swzs = ((lane & 7) ^ r8) << 4;         // staging swizzle (bytes)
  const int swzr = (l15 & 7) << 4;                 // read swizzle (bytes)

  for (int sb = 0; sb < nsb; ++sb) {
    const int srow0 = (sb < 8) ? sb * 64 : TSEQ + g * TSEQ + (sb - 8) * 64;
    const int scol = sb * 64;

    __syncthreads();   // prior compute done; K/V LDS free
    {
      // K rows wid*16 .. +15 (2 insts x 8 rows), pre-swizzled source
      const ushort_t* ks = Kb + ((size_t)bh * TGT + srow0 + wid * 16 + r8) * HD + (swzs >> 1);
      gload16(ks, kbuf + wid * 2048 + lane * 16);
      gload16(ks + 8 * HD, kbuf + wid * 2048 + 1024 + lane * 16);
      // V rows d = wid*16 .. +15
      const ushort_t* vs = Vt + ((size_t)bh * HD + wid * 16 + r8) * TGT + srow0 + (swzs >> 1);
      gload16(vs, vbuf + wid * 2048 + lane * 16);
      gload16(vs + 8 * TGT, vbuf + wid * 2048 + 1024 + lane * 16);
    }
    __syncthreads();   // staging complete (vmcnt drained by barrier)

    // ---- K fragments from LDS (shared across both half-tiles)
    bf8 kf[4][2];
#pragma unroll
    for (int j = 0; j < 4; ++j) {
      const int row = j * 16 + l15;
      kf[j][0] = *reinterpret_cast<const bf8*>(kbuf + row * 128 + ((l4 * 16) ^ swzr));
      kf[j][1] = *reinterpret_cast<const bf8*>(kbuf + row * 128 + ((64 + l4 * 16) ^ swzr));
    }

#pragma unroll
    for (int th = 0; th < 2; ++th) {
      // combined words for this th (issued early; L2 latency hides under MFMA)
      const unsigned int* cwp = cb[th] + scol + l4 * 4;
      const uint4 c0 = *reinterpret_cast<const uint4*>(cwp);
      const uint4 c1 = *reinterpret_cast<const uint4*>(cwp + 16);
      const uint4 c2 = *reinterpret_cast<const uint4*>(cwp + 32);
      const uint4 c3 = *reinterpret_cast<const uint4*>(cwp + 48);
      const unsigned int cwa[4][4] = {{c0.x, c0.y, c0.z, c0.w},
                                      {c1.x, c1.y, c1.z, c1.w},
                                      {c2.x, c2.y, c2.z, c2.w},
                                      {c3.x, c3.y, c3.z, c3.w}};
      // QK^T (swapped): st[j] cols t=l15, rows s in regs
      f32x4 st[4];
#pragma unroll
      for (int j = 0; j < 4; ++j) {
        f32x4 s4 = {};
        s4 = mfma_bf16(kf[j][0], qf[th][0], s4);
        s4 = mfma_bf16(kf[j][1], qf[th][1], s4);
        st[j] = s4;
      }
      const ushort_t* vrow = vmt[wid] + (th * 16 + l15) * 32;
      float vals[4][4];
      float mx = -1e30f;
#pragma unroll
      for (int j = 0; j < 4; ++j) {
#pragma unroll
        for (int r = 0; r < 4; ++r) {
          const unsigned int w = cwa[j][r];
          const float v = st[j][r] + bf2f((ushort_t)(w >> 16)) + bf2f(vrow[w & 31u]);
          vals[j][r] = v;
          mx = fmaxf(mx, v);
        }
      }
      mx = fmaxf(mx, __shfl_xor(mx, 16));
      mx = fmaxf(mx, __shfl_xor(mx, 32));
      const float oldm = m_run[th];
      const float newm = fmaxf(oldm, mx);
      const float fct = (oldm <= -1e30f) ? 0.f : __expf(oldm - newm);
      float lsum = 0.f;
#pragma unroll
      for (int j = 0; j < 4; ++j) {
        const float p0 = __expf(vals[j][0] - newm);
        const float p1 = __expf(vals[j][1] - newm);
        const float p2 = __expf(vals[j][2] - newm);
        const float p3 = __expf(vals[j][3] - newm);
        lsum += (p0 + p1) + (p2 + p3);
        pbl[wid][th * 576 + l15 * 36 + j * 8 + l4 * 2 + 0] = packbf(p0, p1);
        pbl[wid][th * 576 + l15 * 36 + j * 8 + l4 * 2 + 1] = packbf(p2, p3);
      }
      lsum += __shfl_xor(lsum, 16);
      lsum += __shfl_xor(lsum, 32);
      l_run[th] = l_run[th] * fct + lsum;
      m_run[th] = newm;

      // rescale oacc rows (factor per output row t = l4*4+r)
      f32x4 rs;
      rs[0] = lanebcast(fct, l4 * 4 + 0);
      rs[1] = lanebcast(fct, l4 * 4 + 1);
      rs[2] = lanebcast(fct, l4 * 4 + 2);
      rs[3] = lanebcast(fct, l4 * 4 + 3);
#pragma unroll
      for (int dt = 0; dt < 4; ++dt) oacc[th][dt] *= rs;

      // PV: A = P[t][s] (per-wave LDS), B = V[d][s] (block LDS, swizzled)
      const ushort_t* pbase = reinterpret_cast<const ushort_t*>(&pbl[wid][th * 576]);
#pragma unroll
      for (int k32 = 0; k32 < 2; ++k32) {
        const bf8 pa = *reinterpret_cast<const bf8*>(pbase + l15 * 72 + k32 * 32 + l4 * 8);
#pragma unroll
        for (int dt = 0; dt < 4; ++dt) {
          const bf8 vb = *reinterpret_cast<const bf8*>(
              vbuf + (dt * 16 + l15) * 128 + ((k32 * 64 + l4 * 16) ^ swzr));
          oacc[th][dt] = mfma_bf16(pa, vb, oacc[th][dt]);
        }
      }
    }
  }

  // ---- epilogue
#pragma unroll
  for (int th = 0; th < 2; ++th) {
    const float linv = 1.f / l_run[th];
    f32x4 bs;
    bs[0] = lanebcast(linv, l4 * 4 + 0);
    bs[1] = lanebcast(linv, l4 * 4 + 1);
    bs[2] = lanebcast(linv, l4 * 4 + 2);
    bs[3] = lanebcast(linv, l4 * 4 + 3);
#pragma unroll
    for (int dt = 0; dt < 4; ++dt) {
#pragma unroll
      for (int r = 0; r < 4; ++r) {
        const int tout = qrow0 + th * 16 + l4 * 4 + r;
        AT[((size_t)tout * BSZN + b) * EMB + h * HD + dt * 16 + l15] =
            f2bf(oacc[th][dt][r] * bs[r]);
      }
    }
  }
}

extern "C" void kernel_launch(void* const* d_in, const int* in_sizes, int n_in,
                              void* d_out, int out_size, void* d_ws, size_t ws_size,
                              hipStream_t stream) {
  const float* query     = (const float*)d_in[0];
  const float* mask_main = (const float*)d_in[1];
  const float* mask_ng   = (const float*)d_in[2];
  const int*   ib_main   = (const int*)d_in[3];
  const int*   ib_rel    = (const int*)d_in[4];
  const float* w_in      = (const float*)d_in[5];
  const float* b_in      = (const float*)d_in[6];
  const float* w_out     = (const float*)d_in[7];
  const float* b_out     = (const float*)d_in[8];
  const float* w_rel     = (const float*)d_in[9];
  const float* b_rel     = (const float*)d_in[10];
  float* out = (float*)d_out;

  // workspace layout (u16 units); AT aliases qbf (dead after gemm<3>)
  ushort_t* qbf    = (ushort_t*)d_ws;            // 6291456
  ushort_t* winbf  = qbf + 6291456;              // 3145728
  ushort_t* woutbf = winbf + 3145728;            // 1048576
  ushort_t* relwbf = woutbf + 1048576;           // 524288
  ushort_t* Qb     = relwbf + 524288;            // 6291456
  ushort_t* Kbuf   = Qb + 6291456;               // 6291456
  ushort_t* Vtb    = Kbuf + 6291456;             // 6291456
  ushort_t* VMh    = Vtb + 6291456;              // 3145728
  unsigned int* comb_main = (unsigned int*)(VMh + 3145728);  // 1048576 u32
  unsigned int* comb_ng   = comb_main + 1048576;             // 4194304 u32
  ushort_t* AT     = qbf;                        // alias

  // fp32 -> bf16 (query + weights)
  {
    const int total4 = 1572864 + 786432 + 262144 + 131072;
    cvt4_kernel<<<(total4 + 255) / 256, 256, 0, stream>>>(query, w_in, w_out, w_rel,
                                                          qbf, winbf, woutbf, relwbf);
  }
  // combined ib+mask
  prep_comb_kernel<<<(262144 + 1048576) / 256, 256, 0, stream>>>(
      ib_main, ib_rel, mask_main, mask_ng, comb_main, comb_ng);

  // in-projection -> Q/K/Vt
  gemm_bt<0><<<dim3(24, 48), 256, 0, stream>>>(qbf, winbf, b_in, nullptr,
                                               Qb, Kbuf, Vtb, MROWS, 3072, 1024);
  // relative-value table VMh [b*16+h][t][nb]
  gemm_bt<3><<<dim3(4, 48), 256, 0, stream>>>(qbf, relwbf, b_rel, nullptr,
                                              VMh, nullptr, nullptr, MROWS, 512, 1024);
  // fused attention
  attn_kernel<<<768, 256, 0, stream>>>(Qb, Kbuf, Vtb, VMh, comb_main, comb_ng, AT);
  // out-projection
  gemm_bt<2><<<dim3(8, 48), 256, 0, stream>>>(AT, woutbf, b_out, out,
                                              nullptr, nullptr, nullptr, MROWS, 1024, 1024);
}

// Round 8
// 217.603 us; speedup vs baseline: 1.9503x; 1.1224x over previous
//
#include <hip/hip_runtime.h>

#define TSEQ 512
#define BSZN 4
#define NH 16
#define NBN 32
#define EMB 1024
#define HD 64
#define TGT 1536
#define MROWS 6144

typedef unsigned short ushort_t;
typedef __bf16 bf8 __attribute__((ext_vector_type(8)));
typedef ushort_t u16x8v __attribute__((ext_vector_type(8)));
typedef float f32x4 __attribute__((ext_vector_type(4)));

__device__ __forceinline__ unsigned short f2bf(float f) {
  unsigned int u = __builtin_bit_cast(unsigned int, f);
  u += 0x7fffu + ((u >> 16) & 1u);
  return (unsigned short)(u >> 16);
}

__device__ __forceinline__ float bf2f(unsigned short u) {
  return __builtin_bit_cast(float, (unsigned int)u << 16);
}

__device__ __forceinline__ unsigned int packbf(float a, float b) {
  return (unsigned int)f2bf(a) | ((unsigned int)f2bf(b) << 16);
}

__device__ __forceinline__ void gload16(const void* g, void* l) {
  __builtin_amdgcn_global_load_lds(
      (const __attribute__((address_space(1))) void*)g,
      (__attribute__((address_space(3))) void*)l, 16, 0, 0);
}

__device__ __forceinline__ f32x4 mfma_bf16(bf8 a, bf8 b, f32x4 c) {
  return __builtin_amdgcn_mfma_f32_16x16x32_bf16(a, b, c, 0, 0, 0);
}

__device__ __forceinline__ float lanebcast(float v, int srclane) {
  return __builtin_bit_cast(float,
      __builtin_amdgcn_ds_bpermute(srclane * 4, __builtin_bit_cast(int, v)));
}

// ---------------- fp32 -> bf16 convert (4 segments) ----------------
__global__ void cvt4_kernel(const float* __restrict__ q, const float* __restrict__ win,
                            const float* __restrict__ wout, const float* __restrict__ wrel,
                            ushort_t* __restrict__ qo, ushort_t* __restrict__ wino,
                            ushort_t* __restrict__ wouto, ushort_t* __restrict__ wrelo) {
  const int i = blockIdx.x * blockDim.x + threadIdx.x;
  const int n0 = 1572864, n1 = 786432, n2 = 262144, n3 = 131072;
  const float* src;
  ushort_t* dst;
  int off;
  if (i < n0) { src = q; dst = qo; off = i; }
  else if (i < n0 + n1) { src = win; dst = wino; off = i - n0; }
  else if (i < n0 + n1 + n2) { src = wout; dst = wouto; off = i - n0 - n1; }
  else if (i < n0 + n1 + n2 + n3) { src = wrel; dst = wrelo; off = i - n0 - n1 - n2; }
  else return;
  const float4 v = reinterpret_cast<const float4*>(src)[off];
  ushort4 o;
  o.x = f2bf(v.x); o.y = f2bf(v.y); o.z = f2bf(v.z); o.w = f2bf(v.w);
  reinterpret_cast<ushort4*>(dst)[off] = o;
}

// ---------------- combined (bf16 mask << 16) | bucket  ----------------
__global__ void prep_comb_kernel(const int* __restrict__ ibm, const int* __restrict__ ibr,
                                 const float* __restrict__ mm, const float* __restrict__ mng,
                                 unsigned int* __restrict__ cm, unsigned int* __restrict__ cng) {
  const int i = blockIdx.x * blockDim.x + threadIdx.x;
  const int nm = 262144;   // main u32x4 groups
  const int nr = 1048576;  // ng u32x4 groups
  if (i < nm) {
    const int f = i * 4;
    const int4 ib = *reinterpret_cast<const int4*>(ibm + f);
    const float4 mk = *reinterpret_cast<const float4*>(mm + (f & 262143));
    uint4 o;
    o.x = ((unsigned int)f2bf(mk.x) << 16) | ((unsigned int)ib.x & 31u);
    o.y = ((unsigned int)f2bf(mk.y) << 16) | ((unsigned int)ib.y & 31u);
    o.z = ((unsigned int)f2bf(mk.z) << 16) | ((unsigned int)ib.z & 31u);
    o.w = ((unsigned int)f2bf(mk.w) << 16) | ((unsigned int)ib.w & 31u);
    *reinterpret_cast<uint4*>(cm + f) = o;
  } else if (i < nm + nr) {
    const int f = (i - nm) * 4;
    const int ib_off = ((f >> 20) << 19) + (f & 524287);
    const int mk_off = f & 1048575;
    const int4 ib = *reinterpret_cast<const int4*>(ibr + ib_off);
    const float4 mk = *reinterpret_cast<const float4*>(mng + mk_off);
    uint4 o;
    o.x = ((unsigned int)f2bf(mk.x) << 16) | ((unsigned int)ib.x & 31u);
    o.y = ((unsigned int)f2bf(mk.y) << 16) | ((unsigned int)ib.y & 31u);
    o.z = ((unsigned int)f2bf(mk.z) << 16) | ((unsigned int)ib.z & 31u);
    o.w = ((unsigned int)f2bf(mk.w) << 16) | ((unsigned int)ib.w & 31u);
    *reinterpret_cast<uint4*>(cng + f) = o;
  }
}

// ---------------- GEMM: C[M,N] = A[M,K] * B[N,K]^T + bias ----------------
// BK=64, XOR-swizzled LDS (slot ^= row&7, 16B slots), single-buffered.
// MODE 0: qkv proj -> Q(scaled)/K [bh][t][hd]; Vt [bh][d][t] via LDS transpose
// MODE 2: fp32 C
// MODE 3: bf16 VMh layout [b*16+h][qglob][nb]
template <int MODE>
__global__ __launch_bounds__(256) void gemm_bt(
    const ushort_t* __restrict__ A, const ushort_t* __restrict__ B,
    const float* __restrict__ bias, float* __restrict__ Cf,
    ushort_t* __restrict__ Qo, ushort_t* __restrict__ Ko, ushort_t* __restrict__ Vto,
    int M, int N, int K) {
  __shared__ ushort_t lds[16384];   // lA 8192 | lB 8192 (reused as 32KB transpose buf)
  ushort_t* lA = lds;
  ushort_t* lB = lds + 8192;

  const int tid = threadIdx.x;
  const int lane = tid & 63;
  const int wid = tid >> 6;
  const int l15 = lane & 15, l4 = lane >> 4;
  const int bm = blockIdx.y, bn = blockIdx.x;
  const int wm = (wid >> 1) * 64, wn = (wid & 1) * 64;

  f32x4 acc[4][4] = {};

  // staging: thread stages 4x16B of A and B; row r8, swizzled col slot
  const int r8 = tid >> 3;                       // 0..31
  const int c8 = ((tid & 7) ^ (r8 & 7)) * 8;     // pre-swizzled source col (u16)
  const ushort_t* Ag = A + (size_t)(bm * 128 + r8) * K + c8;
  const ushort_t* Bg = B + (size_t)(bn * 128 + r8) * K + c8;
  ushort_t* lAp = lA + tid * 8;
  ushort_t* lBp = lB + tid * 8;

  for (int kt = 0; kt < K; kt += 64) {
    __syncthreads();
#pragma unroll
    for (int i = 0; i < 4; ++i) {
      gload16(Ag + (size_t)i * 32 * K + kt, lAp + i * 2048);
      gload16(Bg + (size_t)i * 32 * K + kt, lBp + i * 2048);
    }
    __syncthreads();
#pragma unroll
    for (int k0 = 0; k0 < 2; ++k0) {
      bf8 af[4], bv[4];
#pragma unroll
      for (int mi = 0; mi < 4; ++mi) {
        const int row = wm + mi * 16 + l15;
        const int slot = (k0 * 4 + l4) ^ (row & 7);
        af[mi] = *reinterpret_cast<const bf8*>(lA + row * 64 + slot * 8);
      }
#pragma unroll
      for (int ni = 0; ni < 4; ++ni) {
        const int row = wn + ni * 16 + l15;
        const int slot = (k0 * 4 + l4) ^ (row & 7);
        bv[ni] = *reinterpret_cast<const bf8*>(lB + row * 64 + slot * 8);
      }
#pragma unroll
      for (int mi = 0; mi < 4; ++mi)
#pragma unroll
        for (int ni = 0; ni < 4; ++ni)
          acc[mi][ni] = mfma_bf16(af[mi], bv[ni], acc[mi][ni]);
    }
  }

  if (MODE == 0 && bn >= 16) {
    // ---- Vt part: transpose through LDS, store full 64B lines
    __syncthreads();   // all lA/lB reads done; reuse lds as T2[col][bb][t] (swizzled)
    char* tb = reinterpret_cast<char*>(lds);
#pragma unroll
    for (int ni = 0; ni < 4; ++ni) {
      const int colloc = wn + ni * 16 + l15;
      const float bc = bias[bn * 128 + colloc];
      const unsigned int swz = (colloc & 7) << 4;
#pragma unroll
      for (int mi = 0; mi < 4; ++mi) {
        const int t_loc = (wm >> 2) + mi * 4 + l4;        // 0..31
        f32x4 v = acc[mi][ni];
#pragma unroll
        for (int r = 0; r < 4; ++r) {
          const int byteoff = colloc * 256 + ((r * 64 + t_loc * 2) ^ swz);
          *reinterpret_cast<ushort_t*>(tb + byteoff) = f2bf(v[r] + bc);
        }
      }
    }
    __syncthreads();
    const int tglob0 = bm * 32;
#pragma unroll
    for (int p = 0; p < 2; ++p) {
      const int pair = wid * 2 + p;          // 0..7 = (bb, hl)
      const int bb = pair >> 1;
      const int hl = pair & 1;
      const int hh = (bn - 16) * 2 + hl;
      const int bh = bb * NH + hh;
      const int tch = lane & 3;
#pragma unroll
      for (int ii = 0; ii < 4; ++ii) {
        const int dloc = ii * 16 + (lane >> 2);
        const int colloc = hl * 64 + dloc;
        const int byteoff = colloc * 256 + ((bb * 64 + tch * 16) ^ ((colloc & 7) << 4));
        const u16x8v val = *reinterpret_cast<const u16x8v*>(tb + byteoff);
        *reinterpret_cast<u16x8v*>(
            Vto + ((size_t)bh * HD + dloc) * TGT + tglob0 + tch * 8) = val;
      }
    }
    return;
  }

#pragma unroll
  for (int ni = 0; ni < 4; ++ni) {
    const int col = bn * 128 + wn + ni * 16 + l15;
    const float bc = bias[col];
#pragma unroll
    for (int mi = 0; mi < 4; ++mi) {
      const int row0 = bm * 128 + wm + mi * 16 + l4 * 4;
      f32x4 v = acc[mi][ni];
#pragma unroll
      for (int r = 0; r < 4; ++r) {
        const int row = row0 + r;
        float val = v[r] + bc;
        if (MODE == 0) {
          const int part = col >> 10;
          const int cc = col & 1023;
          const int h = cc >> 6, d = cc & 63;
          const int t = row >> 2, bb = row & 3;
          const int bh = bb * NH + h;
          if (part == 0) {
            Qo[((size_t)bh * TGT + t) * HD + d] = f2bf(val * 0.125f);
          } else {
            Ko[((size_t)bh * TGT + t) * HD + d] = f2bf(val);
          }
        } else if (MODE == 3) {
          const int hh = col & 15, nb = col >> 4;
          const int qg = row >> 2, bb2 = row & 3;
          Qo[(((size_t)(bb2 * NH + hh)) * TGT + qg) * NBN + nb] = f2bf(val);
        } else {
          Cf[(size_t)row * N + col] = val;
        }
      }
    }
  }
}

// ---------------- fused attention: block = (b,h,z,128 q-rows), 4 waves x 32 rows ----------
__global__ __launch_bounds__(256, 3) void attn_kernel(
    const ushort_t* __restrict__ Q, const ushort_t* __restrict__ Kb,
    const ushort_t* __restrict__ Vt, const ushort_t* __restrict__ VMh,
    const unsigned int* __restrict__ comb_main, const unsigned int* __restrict__ comb_ng,
    ushort_t* __restrict__ AT) {
  __shared__ unsigned char kbuf[8192];   // K subblock [64 s][64 d] bf16, swizzled
  __shared__ unsigned char vbuf[8192];   // V subblock [64 d][64 s] bf16, swizzled
  __shared__ ushort_t vmt[4][1024];      // per wave [32 t][32 nb] bf16, linear
  __shared__ unsigned int pbl[4][1152];  // per wave, 2 th x [16 t][36 dw]

  const int tid = threadIdx.x;
  const int lane = tid & 63, wid = tid >> 6;
  const int l15 = lane & 15, l4 = lane >> 4;

  const int n = blockIdx.x;
  const int xcd = n & 7;
  const int b = xcd >> 1;
  const int idx = (xcd & 1) * 96 + (n >> 3);   // [0,192)
  const int h = idx / 12;
  const int rem = idx - h * 12;
  const int z = rem >> 2;
  const int blk = rem & 3;
  const int g = (z == 0) ? 0 : z - 1;
  const int bh = b * NH + h;
  const int t0 = blk * 128 + wid * 32;
  const int qrow0 = (z == 0) ? t0 : TSEQ + g * TSEQ + t0;
  const int nsb = (z == 0) ? 8 : 16;

  gload16(VMh + ((size_t)bh * TGT + qrow0 + (lane >> 2)) * NBN + (lane & 3) * 8,
          (ushort_t*)vmt[wid] + lane * 8);
  gload16(VMh + ((size_t)bh * TGT + qrow0 + 16 + (lane >> 2)) * NBN + (lane & 3) * 8,
          (ushort_t*)vmt[wid] + 512 + lane * 8);

  bf8 qf[2][2];
#pragma unroll
  for (int th = 0; th < 2; ++th)
#pragma unroll
    for (int hf = 0; hf < 2; ++hf)
      qf[th][hf] = *reinterpret_cast<const bf8*>(
          &Q[((size_t)bh * TGT + qrow0 + th * 16 + l15) * HD + hf * 32 + l4 * 8]);

  const unsigned int* cb[2];
  {
    const unsigned int* cbase = (z == 0)
        ? comb_main + (size_t)b * TSEQ * TSEQ
        : comb_ng + (size_t)(b * 2 + g) * TSEQ * (2 * TSEQ);
    const int sstr = (z == 0) ? TSEQ : 2 * TSEQ;
    cb[0] = cbase + (size_t)(t0 + l15) * sstr;
    cb[1] = cbase + (size_t)(t0 + 16 + l15) * sstr;
  }

  float m_run[2] = {-1e30f, -1e30f};
  float l_run[2] = {0.f, 0.f};
  f32x4 oacc[2][4] = {};

  const int r8 = lane >> 3;
  const int swzs = ((lane & 7) ^ r8) << 4;
  const int swzr = (l15 & 7) << 4;

  for (int sb = 0; sb < nsb; ++sb) {
    const int srow0 = (sb < 8) ? sb * 64 : TSEQ + g * TSEQ + (sb - 8) * 64;
    const int scol = sb * 64;

    __syncthreads();
    {
      const ushort_t* ks = Kb + ((size_t)bh * TGT + srow0 + wid * 16 + r8) * HD + (swzs >> 1);
      gload16(ks, kbuf + wid * 2048 + lane * 16);
      gload16(ks + 8 * HD, kbuf + wid * 2048 + 1024 + lane * 16);
      const ushort_t* vs = Vt + ((size_t)bh * HD + wid * 16 + r8) * TGT + srow0 + (swzs >> 1);
      gload16(vs, vbuf + wid * 2048 + lane * 16);
      gload16(vs + 8 * TGT, vbuf + wid * 2048 + 1024 + lane * 16);
    }
    __syncthreads();

    bf8 kf[4][2];
#pragma unroll
    for (int j = 0; j < 4; ++j) {
      const int row = j * 16 + l15;
      kf[j][0] = *reinterpret_cast<const bf8*>(kbuf + row * 128 + ((l4 * 16) ^ swzr));
      kf[j][1] = *reinterpret_cast<const bf8*>(kbuf + row * 128 + ((64 + l4 * 16) ^ swzr));
    }

#pragma unroll
    for (int th = 0; th < 2; ++th) {
      const unsigned int* cwp = cb[th] + scol + l4 * 4;
      const uint4 c0 = *reinterpret_cast<const uint4*>(cwp);
      const uint4 c1 = *reinterpret_cast<const uint4*>(cwp + 16);
      const uint4 c2 = *reinterpret_cast<const uint4*>(cwp + 32);
      const uint4 c3 = *reinterpret_cast<const uint4*>(cwp + 48);
      const unsigned int cwa[4][4] = {{c0.x, c0.y, c0.z, c0.w},
                                      {c1.x, c1.y, c1.z, c1.w},
                                      {c2.x, c2.y, c2.z, c2.w},
                                      {c3.x, c3.y, c3.z, c3.w}};
      f32x4 st[4];
#pragma unroll
      for (int j = 0; j < 4; ++j) {
        f32x4 s4 = {};
        s4 = mfma_bf16(kf[j][0], qf[th][0], s4);
        s4 = mfma_bf16(kf[j][1], qf[th][1], s4);
        st[j] = s4;
      }
      const ushort_t* vrow = vmt[wid] + (th * 16 + l15) * 32;
      float vals[4][4];
      float mx = -1e30f;
#pragma unroll
      for (int j = 0; j < 4; ++j) {
#pragma unroll
        for (int r = 0; r < 4; ++r) {
          const unsigned int w = cwa[j][r];
          const float v = st[j][r] + bf2f((ushort_t)(w >> 16)) + bf2f(vrow[w & 31u]);
          vals[j][r] = v;
          mx = fmaxf(mx, v);
        }
      }
      mx = fmaxf(mx, __shfl_xor(mx, 16));
      mx = fmaxf(mx, __shfl_xor(mx, 32));
      const float oldm = m_run[th];
      const float newm = fmaxf(oldm, mx);
      const float fct = (oldm <= -1e30f) ? 0.f : __expf(oldm - newm);
      float lsum = 0.f;
#pragma unroll
      for (int j = 0; j < 4; ++j) {
        const float p0 = __expf(vals[j][0] - newm);
        const float p1 = __expf(vals[j][1] - newm);
        const float p2 = __expf(vals[j][2] - newm);
        const float p3 = __expf(vals[j][3] - newm);
        lsum += (p0 + p1) + (p2 + p3);
        pbl[wid][th * 576 + l15 * 36 + j * 8 + l4 * 2 + 0] = packbf(p0, p1);
        pbl[wid][th * 576 + l15 * 36 + j * 8 + l4 * 2 + 1] = packbf(p2, p3);
      }
      lsum += __shfl_xor(lsum, 16);
      lsum += __shfl_xor(lsum, 32);
      l_run[th] = l_run[th] * fct + lsum;
      m_run[th] = newm;

      f32x4 rs;
      rs[0] = lanebcast(fct, l4 * 4 + 0);
      rs[1] = lanebcast(fct, l4 * 4 + 1);
      rs[2] = lanebcast(fct, l4 * 4 + 2);
      rs[3] = lanebcast(fct, l4 * 4 + 3);
#pragma unroll
      for (int dt = 0; dt < 4; ++dt) oacc[th][dt] *= rs;

      const ushort_t* pbase = reinterpret_cast<const ushort_t*>(&pbl[wid][th * 576]);
#pragma unroll
      for (int k32 = 0; k32 < 2; ++k32) {
        const bf8 pa = *reinterpret_cast<const bf8*>(pbase + l15 * 72 + k32 * 32 + l4 * 8);
#pragma unroll
        for (int dt = 0; dt < 4; ++dt) {
          const bf8 vb = *reinterpret_cast<const bf8*>(
              vbuf + (dt * 16 + l15) * 128 + ((k32 * 64 + l4 * 16) ^ swzr));
          oacc[th][dt] = mfma_bf16(pa, vb, oacc[th][dt]);
        }
      }
    }
  }

#pragma unroll
  for (int th = 0; th < 2; ++th) {
    const float linv = 1.f / l_run[th];
    f32x4 bs;
    bs[0] = lanebcast(linv, l4 * 4 + 0);
    bs[1] = lanebcast(linv, l4 * 4 + 1);
    bs[2] = lanebcast(linv, l4 * 4 + 2);
    bs[3] = lanebcast(linv, l4 * 4 + 3);
#pragma unroll
    for (int dt = 0; dt < 4; ++dt) {
#pragma unroll
      for (int r = 0; r < 4; ++r) {
        const int tout = qrow0 + th * 16 + l4 * 4 + r;
        AT[((size_t)tout * BSZN + b) * EMB + h * HD + dt * 16 + l15] =
            f2bf(oacc[th][dt][r] * bs[r]);
      }
    }
  }
}

extern "C" void kernel_launch(void* const* d_in, const int* in_sizes, int n_in,
                              void* d_out, int out_size, void* d_ws, size_t ws_size,
                              hipStream_t stream) {
  const float* query     = (const float*)d_in[0];
  const float* mask_main = (const float*)d_in[1];
  const float* mask_ng   = (const float*)d_in[2];
  const int*   ib_main   = (const int*)d_in[3];
  const int*   ib_rel    = (const int*)d_in[4];
  const float* w_in      = (const float*)d_in[5];
  const float* b_in      = (const float*)d_in[6];
  const float* w_out     = (const float*)d_in[7];
  const float* b_out     = (const float*)d_in[8];
  const float* w_rel     = (const float*)d_in[9];
  const float* b_rel     = (const float*)d_in[10];
  float* out = (float*)d_out;

  // workspace layout (u16 units); AT aliases qbf (dead after gemm<3>)
  ushort_t* qbf    = (ushort_t*)d_ws;            // 6291456
  ushort_t* winbf  = qbf + 6291456;              // 3145728
  ushort_t* woutbf = winbf + 3145728;            // 1048576
  ushort_t* relwbf = woutbf + 1048576;           // 524288
  ushort_t* Qb     = relwbf + 524288;            // 6291456
  ushort_t* Kbuf   = Qb + 6291456;               // 6291456
  ushort_t* Vtb    = Kbuf + 6291456;             // 6291456
  ushort_t* VMh    = Vtb + 6291456;              // 3145728
  unsigned int* comb_main = (unsigned int*)(VMh + 3145728);  // 1048576 u32
  unsigned int* comb_ng   = comb_main + 1048576;             // 4194304 u32
  ushort_t* AT     = qbf;                        // alias

  // fp32 -> bf16 (query + weights)
  {
    const int total4 = 1572864 + 786432 + 262144 + 131072;
    cvt4_kernel<<<(total4 + 255) / 256, 256, 0, stream>>>(query, w_in, w_out, w_rel,
                                                          qbf, winbf, woutbf, relwbf);
  }
  // combined ib+mask
  prep_comb_kernel<<<(262144 + 1048576) / 256, 256, 0, stream>>>(
      ib_main, ib_rel, mask_main, mask_ng, comb_main, comb_ng);

  // in-projection -> Q/K/Vt
  gemm_bt<0><<<dim3(24, 48), 256, 0, stream>>>(qbf, winbf, b_in, nullptr,
                                               Qb, Kbuf, Vtb, MROWS, 3072, 1024);
  // relative-value table VMh [b*16+h][t][nb]
  gemm_bt<3><<<dim3(4, 48), 256, 0, stream>>>(qbf, relwbf, b_rel, nullptr,
                                              VMh, nullptr, nullptr, MROWS, 512, 1024);
  // fused attention
  attn_kernel<<<768, 256, 0, stream>>>(Qb, Kbuf, Vtb, VMh, comb_main, comb_ng, AT);
  // out-projection
  gemm_bt<2><<<dim3(8, 48), 256, 0, stream>>>(AT, woutbf, b_out, out,
                                              nullptr, nullptr, nullptr, MROWS, 1024, 1024);
}

// Round 9
// 212.938 us; speedup vs baseline: 1.9930x; 1.0219x over previous
//
#include <hip/hip_runtime.h>

#define TSEQ 512
#define BSZN 4
#define NH 16
#define NBN 32
#define EMB 1024
#define HD 64
#define TGT 1536
#define MROWS 6144
#define LOG2E 1.44269504088896f

typedef unsigned short ushort_t;
typedef __bf16 bf8 __attribute__((ext_vector_type(8)));
typedef __bf16 bf2_t __attribute__((ext_vector_type(2)));
typedef ushort_t u16x8v __attribute__((ext_vector_type(8)));
typedef unsigned int u32x2 __attribute__((ext_vector_type(2)));
typedef float f32x4 __attribute__((ext_vector_type(4)));

__device__ __forceinline__ unsigned short f2bf(float f) {
  return __builtin_bit_cast(unsigned short, (__bf16)f);
}

__device__ __forceinline__ float bf2f(unsigned short u) {
  return __builtin_bit_cast(float, (unsigned int)u << 16);
}

__device__ __forceinline__ unsigned int packbf(float a, float b) {
  bf2_t t;
  t[0] = (__bf16)a;
  t[1] = (__bf16)b;
  return __builtin_bit_cast(unsigned int, t);
}

__device__ __forceinline__ void gload16(const void* g, void* l) {
  __builtin_amdgcn_global_load_lds(
      (const __attribute__((address_space(1))) void*)g,
      (__attribute__((address_space(3))) void*)l, 16, 0, 0);
}

__device__ __forceinline__ f32x4 mfma_bf16(bf8 a, bf8 b, f32x4 c) {
  return __builtin_amdgcn_mfma_f32_16x16x32_bf16(a, b, c, 0, 0, 0);
}

__device__ __forceinline__ float lanebcast(float v, int srclane) {
  return __builtin_bit_cast(float,
      __builtin_amdgcn_ds_bpermute(srclane * 4, __builtin_bit_cast(int, v)));
}

// ---------------- fused prep: fp32->bf16 (4 segs) + combined mask|bucket ----------------
// comb word = (bf16(mask*log2e) << 16) | bucket
__global__ void prep_all_kernel(const float* __restrict__ q, const float* __restrict__ win,
                                const float* __restrict__ wout, const float* __restrict__ wrel,
                                const int* __restrict__ ibm, const int* __restrict__ ibr,
                                const float* __restrict__ mm, const float* __restrict__ mng,
                                ushort_t* __restrict__ qo, ushort_t* __restrict__ wino,
                                ushort_t* __restrict__ wouto, ushort_t* __restrict__ wrelo,
                                unsigned int* __restrict__ cm, unsigned int* __restrict__ cng) {
  const int i = blockIdx.x * blockDim.x + threadIdx.x;
  const int n0 = 1572864, n1 = 786432, n2 = 262144, n3 = 131072;
  const int ncvt = n0 + n1 + n2 + n3;
  const int nm = 262144, nr = 1048576;
  if (i < ncvt) {
    const float* src;
    ushort_t* dst;
    int off;
    if (i < n0) { src = q; dst = qo; off = i; }
    else if (i < n0 + n1) { src = win; dst = wino; off = i - n0; }
    else if (i < n0 + n1 + n2) { src = wout; dst = wouto; off = i - n0 - n1; }
    else { src = wrel; dst = wrelo; off = i - n0 - n1 - n2; }
    const float4 v = reinterpret_cast<const float4*>(src)[off];
    ushort4 o;
    o.x = f2bf(v.x); o.y = f2bf(v.y); o.z = f2bf(v.z); o.w = f2bf(v.w);
    reinterpret_cast<ushort4*>(dst)[off] = o;
  } else if (i < ncvt + nm) {
    const int f = (i - ncvt) * 4;
    const int4 ib = *reinterpret_cast<const int4*>(ibm + f);
    const float4 mk = *reinterpret_cast<const float4*>(mm + (f & 262143));
    uint4 o;
    o.x = ((unsigned int)f2bf(mk.x * LOG2E) << 16) | ((unsigned int)ib.x & 31u);
    o.y = ((unsigned int)f2bf(mk.y * LOG2E) << 16) | ((unsigned int)ib.y & 31u);
    o.z = ((unsigned int)f2bf(mk.z * LOG2E) << 16) | ((unsigned int)ib.z & 31u);
    o.w = ((unsigned int)f2bf(mk.w * LOG2E) << 16) | ((unsigned int)ib.w & 31u);
    *reinterpret_cast<uint4*>(cm + f) = o;
  } else if (i < ncvt + nm + nr) {
    const int f = (i - ncvt - nm) * 4;
    const int ib_off = ((f >> 20) << 19) + (f & 524287);
    const int mk_off = f & 1048575;
    const int4 ib = *reinterpret_cast<const int4*>(ibr + ib_off);
    const float4 mk = *reinterpret_cast<const float4*>(mng + mk_off);
    uint4 o;
    o.x = ((unsigned int)f2bf(mk.x * LOG2E) << 16) | ((unsigned int)ib.x & 31u);
    o.y = ((unsigned int)f2bf(mk.y * LOG2E) << 16) | ((unsigned int)ib.y & 31u);
    o.z = ((unsigned int)f2bf(mk.z * LOG2E) << 16) | ((unsigned int)ib.z & 31u);
    o.w = ((unsigned int)f2bf(mk.w * LOG2E) << 16) | ((unsigned int)ib.w & 31u);
    *reinterpret_cast<uint4*>(cng + f) = o;
  }
}

// ---------------- GEMM: C[M,N] = A[M,K] * B[N,K]^T + bias ----------------
// BK=64, XOR-swizzled LDS (slot ^= row&7, 16B slots), single-buffered.
// MODE 0: qkv proj -> Q(scaled by 0.125*log2e)/K [bh][t][hd]; Vt [bh][d][t] via LDS transpose
// MODE 2: fp32 C
// MODE 3: bf16 VMh layout [b*16+h][qglob][nb], scaled by log2e
template <int MODE>
__global__ __launch_bounds__(256) void gemm_bt(
    const ushort_t* __restrict__ A, const ushort_t* __restrict__ B,
    const float* __restrict__ bias, float* __restrict__ Cf,
    ushort_t* __restrict__ Qo, ushort_t* __restrict__ Ko, ushort_t* __restrict__ Vto,
    int M, int N, int K) {
  __shared__ ushort_t lds[16384];   // lA 8192 | lB 8192 (reused as 32KB transpose buf)
  ushort_t* lA = lds;
  ushort_t* lB = lds + 8192;

  const int tid = threadIdx.x;
  const int lane = tid & 63;
  const int wid = tid >> 6;
  const int l15 = lane & 15, l4 = lane >> 4;
  const int bm = blockIdx.y, bn = blockIdx.x;
  const int wm = (wid >> 1) * 64, wn = (wid & 1) * 64;

  f32x4 acc[4][4] = {};

  const int r8 = tid >> 3;                       // 0..31
  const int c8 = ((tid & 7) ^ (r8 & 7)) * 8;     // pre-swizzled source col (u16)
  const ushort_t* Ag = A + (size_t)(bm * 128 + r8) * K + c8;
  const ushort_t* Bg = B + (size_t)(bn * 128 + r8) * K + c8;
  ushort_t* lAp = lA + tid * 8;
  ushort_t* lBp = lB + tid * 8;

  for (int kt = 0; kt < K; kt += 64) {
    __syncthreads();
#pragma unroll
    for (int i = 0; i < 4; ++i) {
      gload16(Ag + (size_t)i * 32 * K + kt, lAp + i * 2048);
      gload16(Bg + (size_t)i * 32 * K + kt, lBp + i * 2048);
    }
    __syncthreads();
#pragma unroll
    for (int k0 = 0; k0 < 2; ++k0) {
      bf8 af[4], bv[4];
#pragma unroll
      for (int mi = 0; mi < 4; ++mi) {
        const int row = wm + mi * 16 + l15;
        const int slot = (k0 * 4 + l4) ^ (row & 7);
        af[mi] = *reinterpret_cast<const bf8*>(lA + row * 64 + slot * 8);
      }
#pragma unroll
      for (int ni = 0; ni < 4; ++ni) {
        const int row = wn + ni * 16 + l15;
        const int slot = (k0 * 4 + l4) ^ (row & 7);
        bv[ni] = *reinterpret_cast<const bf8*>(lB + row * 64 + slot * 8);
      }
#pragma unroll
      for (int mi = 0; mi < 4; ++mi)
#pragma unroll
        for (int ni = 0; ni < 4; ++ni)
          acc[mi][ni] = mfma_bf16(af[mi], bv[ni], acc[mi][ni]);
    }
  }

  if (MODE == 0 && bn >= 16) {
    // ---- Vt part: transpose through LDS, store full 64B lines
    __syncthreads();
    char* tb = reinterpret_cast<char*>(lds);
#pragma unroll
    for (int ni = 0; ni < 4; ++ni) {
      const int colloc = wn + ni * 16 + l15;
      const float bc = bias[bn * 128 + colloc];
      const unsigned int swz = (colloc & 7) << 4;
#pragma unroll
      for (int mi = 0; mi < 4; ++mi) {
        const int t_loc = (wm >> 2) + mi * 4 + l4;        // 0..31
        f32x4 v = acc[mi][ni];
#pragma unroll
        for (int r = 0; r < 4; ++r) {
          const int byteoff = colloc * 256 + ((r * 64 + t_loc * 2) ^ swz);
          *reinterpret_cast<ushort_t*>(tb + byteoff) = f2bf(v[r] + bc);
        }
      }
    }
    __syncthreads();
    const int tglob0 = bm * 32;
#pragma unroll
    for (int p = 0; p < 2; ++p) {
      const int pair = wid * 2 + p;          // 0..7 = (bb, hl)
      const int bb = pair >> 1;
      const int hl = pair & 1;
      const int hh = (bn - 16) * 2 + hl;
      const int bh = bb * NH + hh;
      const int tch = lane & 3;
#pragma unroll
      for (int ii = 0; ii < 4; ++ii) {
        const int dloc = ii * 16 + (lane >> 2);
        const int colloc = hl * 64 + dloc;
        const int byteoff = colloc * 256 + ((bb * 64 + tch * 16) ^ ((colloc & 7) << 4));
        const u16x8v val = *reinterpret_cast<const u16x8v*>(tb + byteoff);
        *reinterpret_cast<u16x8v*>(
            Vto + ((size_t)bh * HD + dloc) * TGT + tglob0 + tch * 8) = val;
      }
    }
    return;
  }

#pragma unroll
  for (int ni = 0; ni < 4; ++ni) {
    const int col = bn * 128 + wn + ni * 16 + l15;
    const float bc = bias[col];
#pragma unroll
    for (int mi = 0; mi < 4; ++mi) {
      const int row0 = bm * 128 + wm + mi * 16 + l4 * 4;
      f32x4 v = acc[mi][ni];
#pragma unroll
      for (int r = 0; r < 4; ++r) {
        const int row = row0 + r;
        float val = v[r] + bc;
        if (MODE == 0) {
          const int part = col >> 10;
          const int cc = col & 1023;
          const int h = cc >> 6, d = cc & 63;
          const int t = row >> 2, bb = row & 3;
          const int bh = bb * NH + h;
          if (part == 0) {
            Qo[((size_t)bh * TGT + t) * HD + d] = f2bf(val * (0.125f * LOG2E));
          } else {
            Ko[((size_t)bh * TGT + t) * HD + d] = f2bf(val);
          }
        } else if (MODE == 3) {
          const int hh = col & 15, nb = col >> 4;
          const int qg = row >> 2, bb2 = row & 3;
          Qo[(((size_t)(bb2 * NH + hh)) * TGT + qg) * NBN + nb] = f2bf(val * LOG2E);
        } else {
          Cf[(size_t)row * N + col] = val;
        }
      }
    }
  }
}

// ---------------- fused attention: block = (b,h,z,128 q-rows), 4 waves x 32 rows ----------
// K/V double-buffered (T3 2-phase: prefetch before compute, vmcnt(0)+s_barrier after).
// exp2 domain (log2e pre-folded); defer-max THR=8; pbl XOR-swizzled like kbuf.
__global__ __launch_bounds__(256, 3) void attn_kernel(
    const ushort_t* __restrict__ Q, const ushort_t* __restrict__ Kb,
    const ushort_t* __restrict__ Vt, const ushort_t* __restrict__ VMh,
    const unsigned int* __restrict__ comb_main, const unsigned int* __restrict__ comb_ng,
    ushort_t* __restrict__ AT) {
  __shared__ unsigned char kbuf[2][8192];  // [64 s][64 d] bf16, swizzled
  __shared__ unsigned char vbuf[2][8192];  // [64 d][64 s] bf16, swizzled
  __shared__ ushort_t vmt[4][1024];        // per wave [32 t][32 nb] bf16 (log2e-scaled)
  __shared__ unsigned int pbl[4][512];     // per wave [16 t][32 dw], XOR-swizzled, th-shared

  const int tid = threadIdx.x;
  const int lane = tid & 63, wid = tid >> 6;
  const int l15 = lane & 15, l4 = lane >> 4;

  const int n = blockIdx.x;
  const int xcd = n & 7;
  const int b = xcd >> 1;
  const int idx = (xcd & 1) * 96 + (n >> 3);   // [0,192)
  const int h = idx / 12;
  const int rem = idx - h * 12;
  const int z = rem >> 2;
  const int blk = rem & 3;
  const int g = (z == 0) ? 0 : z - 1;
  const int bh = b * NH + h;
  const int t0 = blk * 128 + wid * 32;
  const int qrow0 = (z == 0) ? t0 : TSEQ + g * TSEQ + t0;
  const int nsb = (z == 0) ? 8 : 16;

  // ---- stage this wave's VM slab (log2e-scaled bf16)
  gload16(VMh + ((size_t)bh * TGT + qrow0 + (lane >> 2)) * NBN + (lane & 3) * 8,
          (ushort_t*)vmt[wid] + lane * 8);
  gload16(VMh + ((size_t)bh * TGT + qrow0 + 16 + (lane >> 2)) * NBN + (lane & 3) * 8,
          (ushort_t*)vmt[wid] + 512 + lane * 8);

  // ---- Q fragments (B-operand, pre-scaled by 0.125*log2e)
  bf8 qf[2][2];
#pragma unroll
  for (int th = 0; th < 2; ++th)
#pragma unroll
    for (int hf = 0; hf < 2; ++hf)
      qf[th][hf] = *reinterpret_cast<const bf8*>(
          &Q[((size_t)bh * TGT + qrow0 + th * 16 + l15) * HD + hf * 32 + l4 * 8]);

  const unsigned int* cb[2];
  {
    const unsigned int* cbase = (z == 0)
        ? comb_main + (size_t)b * TSEQ * TSEQ
        : comb_ng + (size_t)(b * 2 + g) * TSEQ * (2 * TSEQ);
    const int sstr = (z == 0) ? TSEQ : 2 * TSEQ;
    cb[0] = cbase + (size_t)(t0 + l15) * sstr;
    cb[1] = cbase + (size_t)(t0 + 16 + l15) * sstr;
  }

  float m_run[2] = {-1e30f, -1e30f};
  float l_run[2] = {0.f, 0.f};
  f32x4 oacc[2][4] = {};

  const int r8 = lane >> 3;
  const int swzs = ((lane & 7) ^ r8) << 4;   // staging swizzle (bytes)
  const int swzr = (l15 & 7) << 4;           // read swizzle (bytes)
  const int swz2 = (l15 & 7) << 2;           // pbl dword swizzle

  // stage K/V subblock for sb into buffer `bf`
  auto stage = [&](int sb, int bf) {
    const int srow0 = (sb < 8) ? sb * 64 : TSEQ + g * TSEQ + (sb - 8) * 64;
    const ushort_t* ks = Kb + ((size_t)bh * TGT + srow0 + wid * 16 + r8) * HD + (swzs >> 1);
    gload16(ks, &kbuf[bf][wid * 2048 + lane * 16]);
    gload16(ks + 8 * HD, &kbuf[bf][wid * 2048 + 1024 + lane * 16]);
    const ushort_t* vs = Vt + ((size_t)bh * HD + wid * 16 + r8) * TGT + srow0 + (swzs >> 1);
    gload16(vs, &vbuf[bf][wid * 2048 + lane * 16]);
    gload16(vs + 8 * TGT, &vbuf[bf][wid * 2048 + 1024 + lane * 16]);
  };

  // prologue
  stage(0, 0);
  asm volatile("s_waitcnt vmcnt(0)" ::: "memory");
  __builtin_amdgcn_s_barrier();

  int cur = 0;
  for (int sb = 0; sb < nsb; ++sb) {
    const int scol = sb * 64;
    if (sb + 1 < nsb) stage(sb + 1, cur ^ 1);   // prefetch flies under compute

    const unsigned char* kb = kbuf[cur];
    const unsigned char* vbb = vbuf[cur];

    bf8 kf[4][2];
#pragma unroll
    for (int j = 0; j < 4; ++j) {
      const int row = j * 16 + l15;
      kf[j][0] = *reinterpret_cast<const bf8*>(kb + row * 128 + ((l4 * 16) ^ swzr));
      kf[j][1] = *reinterpret_cast<const bf8*>(kb + row * 128 + ((64 + l4 * 16) ^ swzr));
    }

#pragma unroll
    for (int th = 0; th < 2; ++th) {
      const unsigned int* cwp = cb[th] + scol + l4 * 4;
      const uint4 c0 = *reinterpret_cast<const uint4*>(cwp);
      const uint4 c1 = *reinterpret_cast<const uint4*>(cwp + 16);
      const uint4 c2 = *reinterpret_cast<const uint4*>(cwp + 32);
      const uint4 c3 = *reinterpret_cast<const uint4*>(cwp + 48);
      const unsigned int cwa[4][4] = {{c0.x, c0.y, c0.z, c0.w},
                                      {c1.x, c1.y, c1.z, c1.w},
                                      {c2.x, c2.y, c2.z, c2.w},
                                      {c3.x, c3.y, c3.z, c3.w}};
      f32x4 st[4];
#pragma unroll
      for (int j = 0; j < 4; ++j) {
        f32x4 s4 = {};
        s4 = mfma_bf16(kf[j][0], qf[th][0], s4);
        s4 = mfma_bf16(kf[j][1], qf[th][1], s4);
        st[j] = s4;
      }
      const ushort_t* vrow = vmt[wid] + (th * 16 + l15) * 32;
      float vals[4][4];
      float mx = -1e30f;
#pragma unroll
      for (int j = 0; j < 4; ++j) {
#pragma unroll
        for (int r = 0; r < 4; ++r) {
          const unsigned int w = cwa[j][r];
          const float v = st[j][r] + __builtin_bit_cast(float, w & 0xffff0000u) +
                          bf2f(vrow[w & 31u]);
          vals[j][r] = v;
          mx = fmaxf(mx, v);
        }
      }
      mx = fmaxf(mx, __shfl_xor(mx, 16));
      mx = fmaxf(mx, __shfl_xor(mx, 32));   // per-t max (uniform across l4)

      const float oldm = m_run[th];
      if (!__all(mx - oldm <= 8.f)) {       // defer-max: rescale only on real growth
        const float newm = fmaxf(oldm, mx);
        const float fct = (oldm <= -1e30f) ? 0.f : exp2f(oldm - newm);
        f32x4 rs;
        rs[0] = lanebcast(fct, l4 * 4 + 0);
        rs[1] = lanebcast(fct, l4 * 4 + 1);
        rs[2] = lanebcast(fct, l4 * 4 + 2);
        rs[3] = lanebcast(fct, l4 * 4 + 3);
#pragma unroll
        for (int dt = 0; dt < 4; ++dt) oacc[th][dt] *= rs;
        l_run[th] *= fct;
        m_run[th] = newm;
      }
      const float mref = m_run[th];

      float lsum = 0.f;
#pragma unroll
      for (int j = 0; j < 4; ++j) {
        const float p0 = exp2f(vals[j][0] - mref);
        const float p1 = exp2f(vals[j][1] - mref);
        const float p2 = exp2f(vals[j][2] - mref);
        const float p3 = exp2f(vals[j][3] - mref);
        lsum += (p0 + p1) + (p2 + p3);
        u32x2 pw;
        pw[0] = packbf(p0, p1);
        pw[1] = packbf(p2, p3);
        *reinterpret_cast<u32x2*>(&pbl[wid][l15 * 32 + ((j * 8 + l4 * 2) ^ swz2)]) = pw;
      }
      lsum += __shfl_xor(lsum, 16);
      lsum += __shfl_xor(lsum, 32);
      l_run[th] += lsum;

      // PV: A = P[t][s] (per-wave LDS, swizzled), B = V[d][s] (block LDS, swizzled)
      const unsigned char* pbase = reinterpret_cast<const unsigned char*>(&pbl[wid][0]);
#pragma unroll
      for (int k32 = 0; k32 < 2; ++k32) {
        const bf8 pa = *reinterpret_cast<const bf8*>(
            pbase + l15 * 128 + ((k32 * 64 + l4 * 16) ^ swzr));
#pragma unroll
        for (int dt = 0; dt < 4; ++dt) {
          const bf8 vb = *reinterpret_cast<const bf8*>(
              vbb + (dt * 16 + l15) * 128 + ((k32 * 64 + l4 * 16) ^ swzr));
          oacc[th][dt] = mfma_bf16(pa, vb, oacc[th][dt]);
        }
      }
    }

    asm volatile("s_waitcnt vmcnt(0)" ::: "memory");  // next-buf stage landed (flew under compute)
    __builtin_amdgcn_s_barrier();
    cur ^= 1;
  }

  // ---- epilogue
#pragma unroll
  for (int th = 0; th < 2; ++th) {
    const float linv = 1.f / l_run[th];
    f32x4 bs;
    bs[0] = lanebcast(linv, l4 * 4 + 0);
    bs[1] = lanebcast(linv, l4 * 4 + 1);
    bs[2] = lanebcast(linv, l4 * 4 + 2);
    bs[3] = lanebcast(linv, l4 * 4 + 3);
#pragma unroll
    for (int dt = 0; dt < 4; ++dt) {
#pragma unroll
      for (int r = 0; r < 4; ++r) {
        const int tout = qrow0 + th * 16 + l4 * 4 + r;
        AT[((size_t)tout * BSZN + b) * EMB + h * HD + dt * 16 + l15] =
            f2bf(oacc[th][dt][r] * bs[r]);
      }
    }
  }
}

extern "C" void kernel_launch(void* const* d_in, const int* in_sizes, int n_in,
                              void* d_out, int out_size, void* d_ws, size_t ws_size,
                              hipStream_t stream) {
  const float* query     = (const float*)d_in[0];
  const float* mask_main = (const float*)d_in[1];
  const float* mask_ng   = (const float*)d_in[2];
  const int*   ib_main   = (const int*)d_in[3];
  const int*   ib_rel    = (const int*)d_in[4];
  const float* w_in      = (const float*)d_in[5];
  const float* b_in      = (const float*)d_in[6];
  const float* w_out     = (const float*)d_in[7];
  const float* b_out     = (const float*)d_in[8];
  const float* w_rel     = (const float*)d_in[9];
  const float* b_rel     = (const float*)d_in[10];
  float* out = (float*)d_out;

  // workspace layout (u16 units); AT aliases qbf (dead after gemm<3>)
  ushort_t* qbf    = (ushort_t*)d_ws;            // 6291456
  ushort_t* winbf  = qbf + 6291456;              // 3145728
  ushort_t* woutbf = winbf + 3145728;            // 1048576
  ushort_t* relwbf = woutbf + 1048576;           // 524288
  ushort_t* Qb     = relwbf + 524288;            // 6291456
  ushort_t* Kbuf   = Qb + 6291456;               // 6291456
  ushort_t* Vtb    = Kbuf + 6291456;             // 6291456
  ushort_t* VMh    = Vtb + 6291456;              // 3145728
  unsigned int* comb_main = (unsigned int*)(VMh + 3145728);  // 1048576 u32
  unsigned int* comb_ng   = comb_main + 1048576;             // 4194304 u32
  ushort_t* AT     = qbf;                        // alias

  // fused prep: cvt + comb (mask pre-scaled by log2e)
  {
    const int total = 2752512 + 262144 + 1048576;
    prep_all_kernel<<<(total + 255) / 256, 256, 0, stream>>>(
        query, w_in, w_out, w_rel, ib_main, ib_rel, mask_main, mask_ng,
        qbf, winbf, woutbf, relwbf, comb_main, comb_ng);
  }

  // in-projection -> Q/K/Vt
  gemm_bt<0><<<dim3(24, 48), 256, 0, stream>>>(qbf, winbf, b_in, nullptr,
                                               Qb, Kbuf, Vtb, MROWS, 3072, 1024);
  // relative-value table VMh [b*16+h][t][nb] (log2e-scaled)
  gemm_bt<3><<<dim3(4, 48), 256, 0, stream>>>(qbf, relwbf, b_rel, nullptr,
                                              VMh, nullptr, nullptr, MROWS, 512, 1024);
  // fused attention
  attn_kernel<<<768, 256, 0, stream>>>(Qb, Kbuf, Vtb, VMh, comb_main, comb_ng, AT);
  // out-projection
  gemm_bt<2><<<dim3(8, 48), 256, 0, stream>>>(AT, woutbf, b_out, out,
                                              nullptr, nullptr, nullptr, MROWS, 1024, 1024);
}